// Round 1
// baseline (1567.220 us; speedup 1.0000x reference)
//
#include <hip/hip_runtime.h>

// ---------------------------------------------------------------------------
// VGAE forward: GraphConv(256->128)+ReLU, GraphConv(128->64) x2 (fused),
// reparameterize, then sigmoid(z @ z.T).
// N=16384 nodes, E=262144 edges, out = [pre (N*N), z (N*64)] fp32.
// ---------------------------------------------------------------------------

__global__ void k_deg(const int* __restrict__ src, const int* __restrict__ dst,
                      float* __restrict__ cs, float* __restrict__ cd, int E) {
  int i = blockIdx.x * blockDim.x + threadIdx.x;
  if (i < E) {
    atomicAdd(&cs[src[i]], 1.0f);
    atomicAdd(&cd[dst[i]], 1.0f);
  }
}

__global__ void k_cnorm(float* __restrict__ cs, float* __restrict__ cd, int n) {
  int i = blockIdx.x * blockDim.x + threadIdx.x;
  if (i < n) {
    float a = cs[i]; cs[i] = (a > 0.f) ? rsqrtf(a) : 0.f;
    float b = cd[i]; cd[i] = (b > 0.f) ? rsqrtf(b) : 0.f;
  }
}

// out[r,t] = sum_k (x[r,k]*cs[r]) * W[k,t];  x:[n,256] W:[256,128] out:[n,128]
// 8 rows per 128-thread block; W reads coalesced, x rows broadcast from LDS.
__global__ void __launch_bounds__(128) k_xw1(const float* __restrict__ x,
                                             const float* __restrict__ W,
                                             const float* __restrict__ cs,
                                             float* __restrict__ out) {
  __shared__ float xs[8][256];
  const int rb = blockIdx.x * 8;
  const int t = threadIdx.x;
#pragma unroll
  for (int r = 0; r < 8; ++r) {
    float c = cs[rb + r];
    xs[r][t]       = x[(size_t)(rb + r) * 256 + t] * c;
    xs[r][t + 128] = x[(size_t)(rb + r) * 256 + t + 128] * c;
  }
  __syncthreads();
  float acc[8] = {};
  for (int k = 0; k < 256; ++k) {
    float w = W[k * 128 + t];
#pragma unroll
    for (int r = 0; r < 8; ++r) acc[r] += xs[r][k] * w;
  }
#pragma unroll
  for (int r = 0; r < 8; ++r) out[(size_t)(rb + r) * 128 + t] = acc[r];
}

// Fused second/third conv linear: out[r,0:64]=(h*cs)@Wm, out[r,64:128]=(h*cs)@Ws
__global__ void __launch_bounds__(128) k_xw2(const float* __restrict__ h,
                                             const float* __restrict__ Wm,
                                             const float* __restrict__ Ws,
                                             const float* __restrict__ cs,
                                             float* __restrict__ out) {
  __shared__ float xs[8][128];
  const int rb = blockIdx.x * 8;
  const int t = threadIdx.x;
#pragma unroll
  for (int r = 0; r < 8; ++r) {
    float c = cs[rb + r];
    xs[r][t] = h[(size_t)(rb + r) * 128 + t] * c;
  }
  __syncthreads();
  const float* W = (t < 64) ? Wm : Ws;
  const int col = t & 63;
  float acc[8] = {};
  for (int k = 0; k < 128; ++k) {
    float w = W[k * 64 + col];
#pragma unroll
    for (int r = 0; r < 8; ++r) acc[r] += xs[r][k] * w;
  }
#pragma unroll
  for (int r = 0; r < 8; ++r) out[(size_t)(rb + r) * 128 + t] = acc[r];
}

// Edge scatter-add: agg[dst] += tmp[src], 128 floats/edge, 32 threads/edge.
__global__ void k_scatter128(const float* __restrict__ tmp,
                             const int* __restrict__ src,
                             const int* __restrict__ dst,
                             float* __restrict__ agg, int E) {
  long long tid = (long long)blockIdx.x * blockDim.x + threadIdx.x;
  int e = (int)(tid >> 5);
  if (e >= E) return;
  int sub = ((int)tid & 31) * 4;
  int s = src[e], d = dst[e];
  float4 v = *reinterpret_cast<const float4*>(&tmp[(size_t)s * 128 + sub]);
  float* p = &agg[(size_t)d * 128 + sub];
  atomicAdd(p + 0, v.x);
  atomicAdd(p + 1, v.y);
  atomicAdd(p + 2, v.z);
  atomicAdd(p + 3, v.w);
}

// h = relu(agg * c_dst + b), in place. n*128 elements.
__global__ void k_post1(float* __restrict__ agg, const float* __restrict__ cd,
                        const float* __restrict__ b, int total) {
  int i = blockIdx.x * blockDim.x + threadIdx.x;
  if (i >= total) return;
  int nrow = i >> 7, c = i & 127;
  float v = agg[i] * cd[nrow] + b[c];
  agg[i] = v > 0.f ? v : 0.f;
}

// z = (mean) + noise * exp(log_std); mean = agg[:, :64]*cd+bm, ls = agg[:,64:]*cd+bs
__global__ void k_post2(const float* __restrict__ agg, const float* __restrict__ cd,
                        const float* __restrict__ bm, const float* __restrict__ bs,
                        const float* __restrict__ noise, float* __restrict__ z,
                        int total) {
  int i = blockIdx.x * blockDim.x + threadIdx.x;
  if (i >= total) return;
  int nrow = i >> 6, c = i & 63;
  float cdn = cd[nrow];
  float mean = agg[(size_t)nrow * 128 + c] * cdn + bm[c];
  float ls   = agg[(size_t)nrow * 128 + 64 + c] * cdn + bs[c];
  z[i] = mean + noise[i] * __expf(ls);
}

// pre[i,j] = sigmoid(dot(z[i,:], z[j,:])), z:[n,64]. 64x64 tile per 256-thread
// block, 4x4 outputs/thread. z tiles stored k-major in LDS (pitch 68 floats:
// 16B-aligned float4 rows, <=2-way bank conflicts).
__global__ void __launch_bounds__(256) k_zz(const float* __restrict__ z,
                                            float* __restrict__ pre, int n) {
  __shared__ float zis[64][68];
  __shared__ float zjs[64][68];
  const int bi = blockIdx.y, bj = blockIdx.x;
  const int t = threadIdx.x;
#pragma unroll
  for (int q = 0; q < 4; ++q) {
    int f = t + 256 * q;       // 0..1023 float4 slots
    int row = f >> 4;          // 0..63
    int c4 = (f & 15) << 2;    // 0..60
    float4 vi = *reinterpret_cast<const float4*>(&z[(size_t)(bi * 64 + row) * 64 + c4]);
    float4 vj = *reinterpret_cast<const float4*>(&z[(size_t)(bj * 64 + row) * 64 + c4]);
    zis[c4 + 0][row] = vi.x; zis[c4 + 1][row] = vi.y;
    zis[c4 + 2][row] = vi.z; zis[c4 + 3][row] = vi.w;
    zjs[c4 + 0][row] = vj.x; zjs[c4 + 1][row] = vj.y;
    zjs[c4 + 2][row] = vj.z; zjs[c4 + 3][row] = vj.w;
  }
  __syncthreads();
  const int tx = t & 15, ty = t >> 4;
  float acc[4][4] = {};
  for (int k = 0; k < 64; ++k) {
    float4 a4 = *reinterpret_cast<const float4*>(&zis[k][ty * 4]);
    float4 b4 = *reinterpret_cast<const float4*>(&zjs[k][tx * 4]);
    float av[4] = {a4.x, a4.y, a4.z, a4.w};
    float bv[4] = {b4.x, b4.y, b4.z, b4.w};
#pragma unroll
    for (int r = 0; r < 4; ++r)
#pragma unroll
      for (int c = 0; c < 4; ++c) acc[r][c] += av[r] * bv[c];
  }
#pragma unroll
  for (int r = 0; r < 4; ++r) {
    float4 o;
    o.x = 1.f / (1.f + __expf(-acc[r][0]));
    o.y = 1.f / (1.f + __expf(-acc[r][1]));
    o.z = 1.f / (1.f + __expf(-acc[r][2]));
    o.w = 1.f / (1.f + __expf(-acc[r][3]));
    size_t row = (size_t)(bi * 64 + ty * 4 + r);
    *reinterpret_cast<float4*>(&pre[row * n + bj * 64 + tx * 4]) = o;
  }
}

extern "C" void kernel_launch(void* const* d_in, const int* in_sizes, int n_in,
                              void* d_out, int out_size, void* d_ws, size_t ws_size,
                              hipStream_t stream) {
  const float* feat  = (const float*)d_in[0];
  const float* W1    = (const float*)d_in[1];
  const float* b1    = (const float*)d_in[2];
  const float* Wm    = (const float*)d_in[3];
  const float* bm    = (const float*)d_in[4];
  const float* Ws    = (const float*)d_in[5];
  const float* bs    = (const float*)d_in[6];
  const float* noise = (const float*)d_in[7];
  const int* esrc    = (const int*)d_in[8];
  const int* edst    = (const int*)d_in[9];

  const int N = in_sizes[0] / 256;   // 16384
  const int E = in_sizes[8];         // 262144

  float* out = (float*)d_out;
  float* z   = out + (size_t)N * N;  // z lives in d_out after pre

  char* ws = (char*)d_ws;
  float* c_src = (float*)ws;                       // [N]
  float* c_dst = c_src + N;                        // [N]
  float* bufA  = (float*)(ws + 256 * 1024);        // [N,128] linear outputs
  float* bufB  = bufA + (size_t)N * 128;           // [N,128] agg1 -> h
  float* bufC  = bufB + (size_t)N * 128;           // [N,128] agg2

  // degree norms
  hipMemsetAsync(c_src, 0, (size_t)2 * N * sizeof(float), stream);
  k_deg<<<(E + 255) / 256, 256, 0, stream>>>(esrc, edst, c_src, c_dst, E);
  k_cnorm<<<(N + 255) / 256, 256, 0, stream>>>(c_src, c_dst, N);

  // layer 1: tmp = (x*c_src)@W1 ; agg ; h = relu(agg*c_dst + b1)
  k_xw1<<<N / 8, 128, 0, stream>>>(feat, W1, c_src, bufA);
  hipMemsetAsync(bufB, 0, (size_t)N * 128 * sizeof(float), stream);
  {
    long long th = (long long)E * 32;
    k_scatter128<<<(int)((th + 255) / 256), 256, 0, stream>>>(bufA, esrc, edst, bufB, E);
  }
  k_post1<<<(N * 128 + 255) / 256, 256, 0, stream>>>(bufB, c_dst, b1, N * 128);

  // layers 2+3 fused: tmp = [(h*c)@Wm | (h*c)@Ws] ; agg ; z = mean + noise*exp(ls)
  k_xw2<<<N / 8, 128, 0, stream>>>(bufB, Wm, Ws, c_src, bufA);
  hipMemsetAsync(bufC, 0, (size_t)N * 128 * sizeof(float), stream);
  {
    long long th = (long long)E * 32;
    k_scatter128<<<(int)((th + 255) / 256), 256, 0, stream>>>(bufA, esrc, edst, bufC, E);
  }
  k_post2<<<(N * 64 + 255) / 256, 256, 0, stream>>>(bufC, c_dst, bm, bs, noise, z, N * 64);

  // decoder: pre = sigmoid(z @ z.T)
  dim3 zgrid(N / 64, N / 64);
  k_zz<<<zgrid, 256, 0, stream>>>(z, out, N);
}

// Round 2
// 463.338 us; speedup vs baseline: 3.3825x; 3.3825x over previous
//
#include <hip/hip_runtime.h>
#include <hip/hip_bf16.h>

// ---------------------------------------------------------------------------
// VGAE forward: GraphConv(256->128)+ReLU, GraphConv(128->64) x2 (fused),
// reparameterize, then sigmoid(z @ z.T) via bf16 MFMA.
// N=16384 nodes, E=262144 edges, out = [pre (N*N), z (N*64)] fp32.
// R2: atomic scatter -> CSR gather; decoder -> mfma_f32_16x16x32_bf16.
// ---------------------------------------------------------------------------

typedef short short8 __attribute__((ext_vector_type(8)));
typedef float f32x4 __attribute__((ext_vector_type(4)));

__global__ void k_deg(const int* __restrict__ src, const int* __restrict__ dst,
                      float* __restrict__ cs, float* __restrict__ cd, int E) {
  int i = blockIdx.x * blockDim.x + threadIdx.x;
  if (i < E) {
    atomicAdd(&cs[src[i]], 1.0f);
    atomicAdd(&cd[dst[i]], 1.0f);
  }
}

// Exclusive prefix sum of in-degree counts (float, exact ints) -> off[0..n].
// Single block, 256 threads x 64 nodes each (n == 16384).
__global__ void __launch_bounds__(256) k_scan(const float* __restrict__ cnt,
                                              int* __restrict__ off, int n) {
  __shared__ int sums[256];
  const int t = threadIdx.x;
  const int per = n / 256;
  const int base = t * per;
  int s = 0;
  for (int i = 0; i < per; ++i) s += (int)cnt[base + i];
  sums[t] = s;
  __syncthreads();
  for (int d = 1; d < 256; d <<= 1) {
    int v = (t >= d) ? sums[t - d] : 0;
    __syncthreads();
    sums[t] += v;
    __syncthreads();
  }
  int run = t ? sums[t - 1] : 0;
  for (int i = 0; i < per; ++i) { off[base + i] = run; run += (int)cnt[base + i]; }
  if (t == 255) off[n] = run;
}

__global__ void k_cnorm(float* __restrict__ cs, float* __restrict__ cd, int n) {
  int i = blockIdx.x * blockDim.x + threadIdx.x;
  if (i < n) {
    float a = cs[i]; cs[i] = (a > 0.f) ? rsqrtf(a) : 0.f;
    float b = cd[i]; cd[i] = (b > 0.f) ? rsqrtf(b) : 0.f;
  }
}

// elist[off[d] + pos] = src, grouped by dst. (Order within a node is
// nondeterministic; only perturbs fp sum order at ~1e-7.)
__global__ void k_fill(const int* __restrict__ src, const int* __restrict__ dst,
                       const int* __restrict__ off, int* __restrict__ cursor,
                       int* __restrict__ elist, int E) {
  int e = blockIdx.x * blockDim.x + threadIdx.x;
  if (e < E) {
    int d = dst[e];
    int pos = atomicAdd(&cursor[d], 1);
    elist[off[d] + pos] = src[e];
  }
}

// out[r,t] = sum_k (x[r,k]*cs[r]) * W[k,t];  x:[n,256] W:[256,128] out:[n,128]
__global__ void __launch_bounds__(128) k_xw1(const float* __restrict__ x,
                                             const float* __restrict__ W,
                                             const float* __restrict__ cs,
                                             float* __restrict__ out) {
  __shared__ float xs[8][256];
  const int rb = blockIdx.x * 8;
  const int t = threadIdx.x;
#pragma unroll
  for (int r = 0; r < 8; ++r) {
    float c = cs[rb + r];
    xs[r][t]       = x[(size_t)(rb + r) * 256 + t] * c;
    xs[r][t + 128] = x[(size_t)(rb + r) * 256 + t + 128] * c;
  }
  __syncthreads();
  float acc[8] = {};
  for (int k = 0; k < 256; ++k) {
    float w = W[k * 128 + t];
#pragma unroll
    for (int r = 0; r < 8; ++r) acc[r] += xs[r][k] * w;
  }
#pragma unroll
  for (int r = 0; r < 8; ++r) out[(size_t)(rb + r) * 128 + t] = acc[r];
}

// Fused second/third conv linear: out[r,0:64]=(h*cs)@Wm, out[r,64:128]=(h*cs)@Ws
__global__ void __launch_bounds__(128) k_xw2(const float* __restrict__ h,
                                             const float* __restrict__ Wm,
                                             const float* __restrict__ Ws,
                                             const float* __restrict__ cs,
                                             float* __restrict__ out) {
  __shared__ float xs[8][128];
  const int rb = blockIdx.x * 8;
  const int t = threadIdx.x;
#pragma unroll
  for (int r = 0; r < 8; ++r) {
    float c = cs[rb + r];
    xs[r][t] = h[(size_t)(rb + r) * 128 + t] * c;
  }
  __syncthreads();
  const float* W = (t < 64) ? Wm : Ws;
  const int col = t & 63;
  float acc[8] = {};
  for (int k = 0; k < 128; ++k) {
    float w = W[k * 64 + col];
#pragma unroll
    for (int r = 0; r < 8; ++r) acc[r] += xs[r][k] * w;
  }
#pragma unroll
  for (int r = 0; r < 8; ++r) out[(size_t)(rb + r) * 128 + t] = acc[r];
}

// Layer-1 aggregate (CSR gather) + epilogue: h = relu(agg*cd + b1).
// One 64-lane wave per node; lane owns cols (lane, lane+64).
__global__ void __launch_bounds__(256) k_gather1(const float* __restrict__ tmp,
                                                 const int* __restrict__ off,
                                                 const int* __restrict__ elist,
                                                 const float* __restrict__ cd,
                                                 const float* __restrict__ b,
                                                 float* __restrict__ h) {
  const int node = blockIdx.x * 4 + (threadIdx.x >> 6);
  const int lane = threadIdx.x & 63;
  const int e0 = off[node], e1 = off[node + 1];
  float a0 = 0.f, a1 = 0.f;
  for (int e = e0; e < e1; ++e) {
    const float* p = tmp + (size_t)elist[e] * 128;
    a0 += p[lane];
    a1 += p[lane + 64];
  }
  const float c = cd[node];
  float v0 = a0 * c + b[lane];
  float v1 = a1 * c + b[lane + 64];
  h[(size_t)node * 128 + lane]      = fmaxf(v0, 0.f);
  h[(size_t)node * 128 + lane + 64] = fmaxf(v1, 0.f);
}

// Layer-2/3 aggregate + reparameterize: z = mean + noise*exp(log_std).
// Writes z (fp32, into d_out) and zb (bf16, decoder input).
__global__ void __launch_bounds__(256) k_gather2(const float* __restrict__ tmp,
                                                 const int* __restrict__ off,
                                                 const int* __restrict__ elist,
                                                 const float* __restrict__ cd,
                                                 const float* __restrict__ bm,
                                                 const float* __restrict__ bs,
                                                 const float* __restrict__ noise,
                                                 float* __restrict__ z,
                                                 __hip_bfloat16* __restrict__ zb) {
  const int node = blockIdx.x * 4 + (threadIdx.x >> 6);
  const int lane = threadIdx.x & 63;
  const int e0 = off[node], e1 = off[node + 1];
  float a0 = 0.f, a1 = 0.f;
  for (int e = e0; e < e1; ++e) {
    const float* p = tmp + (size_t)elist[e] * 128;
    a0 += p[lane];        // mean pre-agg
    a1 += p[lane + 64];   // log_std pre-agg
  }
  const float c = cd[node];
  float mean = a0 * c + bm[lane];
  float ls   = a1 * c + bs[lane];
  float zv = mean + noise[(size_t)node * 64 + lane] * __expf(ls);
  z[(size_t)node * 64 + lane]  = zv;
  zb[(size_t)node * 64 + lane] = __float2bfloat16(zv);
}

// pre[i,j] = sigmoid(dot(z[i,:], z[j,:])) via mfma_f32_16x16x32_bf16.
// Block = 4 waves (2x2), 128x128 tile; wave = 64x64 = 4x4 mfma tiles.
// Symmetric operand: B-frag of Z^T == A-frag of Z (lane: row=l&15,
// k=(l>>4)*8+j) -> fragments are direct 16B global loads, no LDS.
__global__ void __launch_bounds__(256) k_zz_mfma(const short* __restrict__ zb,
                                                 float* __restrict__ pre, int n) {
  const int wave = threadIdx.x >> 6, lane = threadIdx.x & 63;
  const int wr = wave >> 1, wc = wave & 1;
  const int brow = blockIdx.y * 128 + wr * 64;
  const int bcol = blockIdx.x * 128 + wc * 64;
  const int lrow = lane & 15;
  const int kq = lane >> 4;  // 0..3

  short8 afrag[2][4], bfrag[2][4];  // [kstep][tile]
#pragma unroll
  for (int tt = 0; tt < 4; ++tt) {
#pragma unroll
    for (int ks = 0; ks < 2; ++ks) {
      afrag[ks][tt] = *reinterpret_cast<const short8*>(
          zb + (size_t)(brow + tt * 16 + lrow) * 64 + ks * 32 + kq * 8);
      bfrag[ks][tt] = *reinterpret_cast<const short8*>(
          zb + (size_t)(bcol + tt * 16 + lrow) * 64 + ks * 32 + kq * 8);
    }
  }

  f32x4 acc[4][4];
#pragma unroll
  for (int i = 0; i < 4; ++i)
#pragma unroll
    for (int j = 0; j < 4; ++j) acc[i][j] = (f32x4){0.f, 0.f, 0.f, 0.f};

#pragma unroll
  for (int i = 0; i < 4; ++i)
#pragma unroll
    for (int j = 0; j < 4; ++j) {
      acc[i][j] = __builtin_amdgcn_mfma_f32_16x16x32_bf16(afrag[0][i], bfrag[0][j], acc[i][j], 0, 0, 0);
      acc[i][j] = __builtin_amdgcn_mfma_f32_16x16x32_bf16(afrag[1][i], bfrag[1][j], acc[i][j], 0, 0, 0);
    }

  // C/D layout: col = lane&15, row = (lane>>4)*4 + reg  [m89-verified]
  const int crow0 = kq * 4;
#pragma unroll
  for (int i = 0; i < 4; ++i) {
#pragma unroll
    for (int r = 0; r < 4; ++r) {
      size_t rowoff = (size_t)(brow + i * 16 + crow0 + r) * (size_t)n;
#pragma unroll
      for (int j = 0; j < 4; ++j) {
        float v = acc[i][j][r];
        pre[rowoff + bcol + j * 16 + lrow] = 1.f / (1.f + __expf(-v));
      }
    }
  }
}

extern "C" void kernel_launch(void* const* d_in, const int* in_sizes, int n_in,
                              void* d_out, int out_size, void* d_ws, size_t ws_size,
                              hipStream_t stream) {
  const float* feat  = (const float*)d_in[0];
  const float* W1    = (const float*)d_in[1];
  const float* b1    = (const float*)d_in[2];
  const float* Wm    = (const float*)d_in[3];
  const float* bm    = (const float*)d_in[4];
  const float* Ws    = (const float*)d_in[5];
  const float* bs    = (const float*)d_in[6];
  const float* noise = (const float*)d_in[7];
  const int* esrc    = (const int*)d_in[8];
  const int* edst    = (const int*)d_in[9];

  const int N = in_sizes[0] / 256;   // 16384
  const int E = in_sizes[8];         // 262144

  float* out = (float*)d_out;
  float* z   = out + (size_t)N * N;  // z lives in d_out after pre

  char* ws = (char*)d_ws;
  float* c_src  = (float*)(ws + 0);                 // [N]
  float* c_dst  = (float*)(ws + 65536);             // [N]
  int*   cursor = (int*)  (ws + 131072);            // [N]
  int*   off    = (int*)  (ws + 196608);            // [N+1]
  int*   elist  = (int*)  (ws + 327680);            // [E]
  float* bufA   = (float*)(ws + 2097152);           // [N,128] linear outputs
  float* bufB   = (float*)(ws + 10485760);          // [N,128] h
  __hip_bfloat16* zb = (__hip_bfloat16*)(ws + 18874368);  // [N,64] bf16 z

  // degree counts + CSR offsets + norms + edge lists
  hipMemsetAsync(ws, 0, 196608, stream);  // c_src, c_dst, cursor
  k_deg<<<(E + 255) / 256, 256, 0, stream>>>(esrc, edst, c_src, c_dst, E);
  k_scan<<<1, 256, 0, stream>>>(c_dst, off, N);
  k_cnorm<<<(N + 255) / 256, 256, 0, stream>>>(c_src, c_dst, N);
  k_fill<<<(E + 255) / 256, 256, 0, stream>>>(esrc, edst, off, cursor, elist, E);

  // layer 1: bufA = (x*c_src)@W1 ; gather+relu -> bufB (h)
  k_xw1<<<N / 8, 128, 0, stream>>>(feat, W1, c_src, bufA);
  k_gather1<<<N / 4, 256, 0, stream>>>(bufA, off, elist, c_dst, b1, bufB);

  // layers 2+3 fused: bufA = [(h*c)@Wm | (h*c)@Ws] ; gather + reparam -> z, zb
  k_xw2<<<N / 8, 128, 0, stream>>>(bufB, Wm, Ws, c_src, bufA);
  k_gather2<<<N / 4, 256, 0, stream>>>(bufA, off, elist, c_dst, bm, bs, noise, z, zb);

  // decoder: pre = sigmoid(z @ z.T), bf16 MFMA
  dim3 zgrid(N / 128, N / 128);
  k_zz_mfma<<<zgrid, 256, 0, stream>>>((const short*)zb, out, N);
}

// Round 3
// 429.954 us; speedup vs baseline: 3.6451x; 1.0776x over previous
//
#include <hip/hip_runtime.h>
#include <hip/hip_bf16.h>

// ---------------------------------------------------------------------------
// VGAE forward: GraphConv(256->128)+ReLU, GraphConv(128->64) x2 (fused via
// linearity), reparameterize, then sigmoid(z @ z.T) via bf16 MFMA.
// N=16384 nodes, E=262144 edges, out = [pre (N*N), z (N*64)] fp32.
// R3: float4 2-edge gathers; k_xw2 folded behind the aggregation (linearity).
// ---------------------------------------------------------------------------

typedef short short8 __attribute__((ext_vector_type(8)));
typedef float f32x4 __attribute__((ext_vector_type(4)));

__global__ void k_deg(const int* __restrict__ src, const int* __restrict__ dst,
                      float* __restrict__ cs, float* __restrict__ cd, int E) {
  int i = blockIdx.x * blockDim.x + threadIdx.x;
  if (i < E) {
    atomicAdd(&cs[src[i]], 1.0f);
    atomicAdd(&cd[dst[i]], 1.0f);
  }
}

// Exclusive prefix sum of in-degree counts -> off[0..n]. Single block.
__global__ void __launch_bounds__(256) k_scan(const float* __restrict__ cnt,
                                              int* __restrict__ off, int n) {
  __shared__ int sums[256];
  const int t = threadIdx.x;
  const int per = n / 256;
  const int base = t * per;
  int s = 0;
  for (int i = 0; i < per; ++i) s += (int)cnt[base + i];
  sums[t] = s;
  __syncthreads();
  for (int d = 1; d < 256; d <<= 1) {
    int v = (t >= d) ? sums[t - d] : 0;
    __syncthreads();
    sums[t] += v;
    __syncthreads();
  }
  int run = t ? sums[t - 1] : 0;
  for (int i = 0; i < per; ++i) { off[base + i] = run; run += (int)cnt[base + i]; }
  if (t == 255) off[n] = run;
}

__global__ void k_cnorm(float* __restrict__ cs, float* __restrict__ cd, int n) {
  int i = blockIdx.x * blockDim.x + threadIdx.x;
  if (i < n) {
    float a = cs[i]; cs[i] = (a > 0.f) ? rsqrtf(a) : 0.f;
    float b = cd[i]; cd[i] = (b > 0.f) ? rsqrtf(b) : 0.f;
  }
}

// elist[off[d] + pos] = src, grouped by dst.
__global__ void k_fill(const int* __restrict__ src, const int* __restrict__ dst,
                       const int* __restrict__ off, int* __restrict__ cursor,
                       int* __restrict__ elist, int E) {
  int e = blockIdx.x * blockDim.x + threadIdx.x;
  if (e < E) {
    int d = dst[e];
    int pos = atomicAdd(&cursor[d], 1);
    elist[off[d] + pos] = src[e];
  }
}

// out[r,t] = sum_k (x[r,k]*cs[r]) * W[k,t];  x:[n,256] W:[256,128] out:[n,128]
__global__ void __launch_bounds__(128) k_xw1(const float* __restrict__ x,
                                             const float* __restrict__ W,
                                             const float* __restrict__ cs,
                                             float* __restrict__ out) {
  __shared__ float xs[8][256];
  const int rb = blockIdx.x * 8;
  const int t = threadIdx.x;
#pragma unroll
  for (int r = 0; r < 8; ++r) {
    float c = cs[rb + r];
    xs[r][t]       = x[(size_t)(rb + r) * 256 + t] * c;
    xs[r][t + 128] = x[(size_t)(rb + r) * 256 + t + 128] * c;
  }
  __syncthreads();
  float acc[8] = {};
  for (int k = 0; k < 256; ++k) {
    float w = W[k * 128 + t];
#pragma unroll
    for (int r = 0; r < 8; ++r) acc[r] += xs[r][k] * w;
  }
#pragma unroll
  for (int r = 0; r < 8; ++r) out[(size_t)(rb + r) * 128 + t] = acc[r];
}

// Layer-1 CSR gather + epilogue. One wave/node, float4 lanes, 2 edges/iter.
// hs[node] = relu(agg*cd + b1) * cs   (cs pre-folded for layer 2)
__global__ void __launch_bounds__(256) k_gather1(const float* __restrict__ tmp,
                                                 const int* __restrict__ off,
                                                 const int* __restrict__ elist,
                                                 const float* __restrict__ cd,
                                                 const float* __restrict__ cs,
                                                 const float* __restrict__ b,
                                                 float* __restrict__ hs) {
  const int node = blockIdx.x * 4 + (threadIdx.x >> 6);
  const int lane = threadIdx.x & 63;
  const int half = lane >> 5;
  const int c4 = (lane & 31) << 2;
  const int e0 = off[node], e1 = off[node + 1];
  f32x4 a = {0.f, 0.f, 0.f, 0.f};
  for (int e = e0 + half; e < e1; e += 2)
    a += *reinterpret_cast<const f32x4*>(tmp + (size_t)elist[e] * 128 + c4);
  a.x += __shfl_xor(a.x, 32);
  a.y += __shfl_xor(a.y, 32);
  a.z += __shfl_xor(a.z, 32);
  a.w += __shfl_xor(a.w, 32);
  if (half == 0) {
    const float c = cd[node], s = cs[node];
    f32x4 bb = *reinterpret_cast<const f32x4*>(b + c4);
    f32x4 r;
    r.x = fmaxf(a.x * c + bb.x, 0.f) * s;
    r.y = fmaxf(a.y * c + bb.y, 0.f) * s;
    r.z = fmaxf(a.z * c + bb.z, 0.f) * s;
    r.w = fmaxf(a.w * c + bb.w, 0.f) * s;
    *reinterpret_cast<f32x4*>(hs + (size_t)node * 128 + c4) = r;
  }
}

// Layer-2/3 shared aggregation: s2c[node] = cd[node] * sum_{src} hs[src]
__global__ void __launch_bounds__(256) k_gather2(const float* __restrict__ hs,
                                                 const int* __restrict__ off,
                                                 const int* __restrict__ elist,
                                                 const float* __restrict__ cd,
                                                 float* __restrict__ s2c) {
  const int node = blockIdx.x * 4 + (threadIdx.x >> 6);
  const int lane = threadIdx.x & 63;
  const int half = lane >> 5;
  const int c4 = (lane & 31) << 2;
  const int e0 = off[node], e1 = off[node + 1];
  f32x4 a = {0.f, 0.f, 0.f, 0.f};
  for (int e = e0 + half; e < e1; e += 2)
    a += *reinterpret_cast<const f32x4*>(hs + (size_t)elist[e] * 128 + c4);
  a.x += __shfl_xor(a.x, 32);
  a.y += __shfl_xor(a.y, 32);
  a.z += __shfl_xor(a.z, 32);
  a.w += __shfl_xor(a.w, 32);
  if (half == 0) {
    const float c = cd[node];
    *reinterpret_cast<f32x4*>(s2c + (size_t)node * 128 + c4) = a * c;
  }
}

// z-finish: z = (s2c @ Wm + bm) + noise * exp(s2c @ Ws + bs); also bf16 copy.
// 8 rows / 128-thread block; thread t owns concat-col t (t<64: Wm, else Ws).
__global__ void __launch_bounds__(128) k_zfin(const float* __restrict__ s2c,
                                              const float* __restrict__ Wm,
                                              const float* __restrict__ Ws,
                                              const float* __restrict__ bm,
                                              const float* __restrict__ bs,
                                              const float* __restrict__ noise,
                                              float* __restrict__ z,
                                              __hip_bfloat16* __restrict__ zb) {
  __shared__ float xs[8][128];
  __shared__ float ys[8][128];
  const int rb = blockIdx.x * 8;
  const int t = threadIdx.x;
#pragma unroll
  for (int r = 0; r < 8; ++r) xs[r][t] = s2c[(size_t)(rb + r) * 128 + t];
  __syncthreads();
  const float* W = (t < 64) ? Wm : Ws;
  const float bias = (t < 64) ? bm[t & 63] : bs[t & 63];
  const int col = t & 63;
  float acc[8] = {};
  for (int k = 0; k < 128; ++k) {
    float w = W[k * 64 + col];
#pragma unroll
    for (int r = 0; r < 8; ++r) acc[r] += xs[r][k] * w;
  }
#pragma unroll
  for (int r = 0; r < 8; ++r) ys[r][t] = acc[r] + bias;
  __syncthreads();
#pragma unroll
  for (int q = 0; q < 4; ++q) {
    int idx = t + 128 * q;            // 0..511
    int row = idx >> 6, c = idx & 63;
    float zv = ys[row][c] + noise[(size_t)(rb + row) * 64 + c] * __expf(ys[row][c + 64]);
    z[(size_t)(rb + row) * 64 + c]  = zv;
    zb[(size_t)(rb + row) * 64 + c] = __float2bfloat16(zv);
  }
}

// pre[i,j] = sigmoid(dot(z[i,:], z[j,:])) via mfma_f32_16x16x32_bf16.
// Block = 4 waves (2x2), 128x128 tile; wave = 64x64 = 4x4 mfma tiles.
__global__ void __launch_bounds__(256) k_zz_mfma(const short* __restrict__ zb,
                                                 float* __restrict__ pre, int n) {
  const int wave = threadIdx.x >> 6, lane = threadIdx.x & 63;
  const int wr = wave >> 1, wc = wave & 1;
  const int brow = blockIdx.y * 128 + wr * 64;
  const int bcol = blockIdx.x * 128 + wc * 64;
  const int lrow = lane & 15;
  const int kq = lane >> 4;  // 0..3

  short8 afrag[2][4], bfrag[2][4];
#pragma unroll
  for (int tt = 0; tt < 4; ++tt) {
#pragma unroll
    for (int ks = 0; ks < 2; ++ks) {
      afrag[ks][tt] = *reinterpret_cast<const short8*>(
          zb + (size_t)(brow + tt * 16 + lrow) * 64 + ks * 32 + kq * 8);
      bfrag[ks][tt] = *reinterpret_cast<const short8*>(
          zb + (size_t)(bcol + tt * 16 + lrow) * 64 + ks * 32 + kq * 8);
    }
  }

  f32x4 acc[4][4];
#pragma unroll
  for (int i = 0; i < 4; ++i)
#pragma unroll
    for (int j = 0; j < 4; ++j) acc[i][j] = (f32x4){0.f, 0.f, 0.f, 0.f};

#pragma unroll
  for (int i = 0; i < 4; ++i)
#pragma unroll
    for (int j = 0; j < 4; ++j) {
      acc[i][j] = __builtin_amdgcn_mfma_f32_16x16x32_bf16(afrag[0][i], bfrag[0][j], acc[i][j], 0, 0, 0);
      acc[i][j] = __builtin_amdgcn_mfma_f32_16x16x32_bf16(afrag[1][i], bfrag[1][j], acc[i][j], 0, 0, 0);
    }

  const int crow0 = kq * 4;
#pragma unroll
  for (int i = 0; i < 4; ++i) {
#pragma unroll
    for (int r = 0; r < 4; ++r) {
      size_t rowoff = (size_t)(brow + i * 16 + crow0 + r) * (size_t)n;
#pragma unroll
      for (int j = 0; j < 4; ++j) {
        float v = acc[i][j][r];
        pre[rowoff + bcol + j * 16 + lrow] = 1.f / (1.f + __expf(-v));
      }
    }
  }
}

extern "C" void kernel_launch(void* const* d_in, const int* in_sizes, int n_in,
                              void* d_out, int out_size, void* d_ws, size_t ws_size,
                              hipStream_t stream) {
  const float* feat  = (const float*)d_in[0];
  const float* W1    = (const float*)d_in[1];
  const float* b1    = (const float*)d_in[2];
  const float* Wm    = (const float*)d_in[3];
  const float* bm    = (const float*)d_in[4];
  const float* Ws    = (const float*)d_in[5];
  const float* bs    = (const float*)d_in[6];
  const float* noise = (const float*)d_in[7];
  const int* esrc    = (const int*)d_in[8];
  const int* edst    = (const int*)d_in[9];

  const int N = in_sizes[0] / 256;   // 16384
  const int E = in_sizes[8];         // 262144

  float* out = (float*)d_out;
  float* z   = out + (size_t)N * N;  // z lives in d_out after pre

  char* ws = (char*)d_ws;
  float* c_src  = (float*)(ws + 0);                 // [N]
  float* c_dst  = (float*)(ws + 65536);             // [N]
  int*   cursor = (int*)  (ws + 131072);            // [N]
  int*   off    = (int*)  (ws + 196608);            // [N+1]
  int*   elist  = (int*)  (ws + 327680);            // [E]
  float* bufA   = (float*)(ws + 2097152);           // [N,128] xw1 out, then s2c
  float* hs     = (float*)(ws + 10485760);          // [N,128] relu(h)*cs
  __hip_bfloat16* zb = (__hip_bfloat16*)(ws + 18874368);  // [N,64] bf16 z

  // degree counts + CSR offsets + norms + edge lists
  hipMemsetAsync(ws, 0, 196608, stream);  // c_src, c_dst, cursor
  k_deg<<<(E + 255) / 256, 256, 0, stream>>>(esrc, edst, c_src, c_dst, E);
  k_scan<<<1, 256, 0, stream>>>(c_dst, off, N);
  k_cnorm<<<(N + 255) / 256, 256, 0, stream>>>(c_src, c_dst, N);
  k_fill<<<(E + 255) / 256, 256, 0, stream>>>(esrc, edst, off, cursor, elist, E);

  // layer 1: bufA = (x*cs)@W1 ; gather -> hs = relu(agg*cd+b1)*cs
  k_xw1<<<N / 8, 128, 0, stream>>>(feat, W1, c_src, bufA);
  k_gather1<<<N / 4, 256, 0, stream>>>(bufA, off, elist, c_dst, c_src, b1, hs);

  // layers 2+3: s2c = cd * agg(hs)  (shared aggregation, W applied after)
  k_gather2<<<N / 4, 256, 0, stream>>>(hs, off, elist, c_dst, bufA);
  k_zfin<<<N / 8, 128, 0, stream>>>(bufA, Wm, Ws, bm, bs, noise, z, zb);

  // decoder: pre = sigmoid(z @ z.T), bf16 MFMA
  dim3 zgrid(N / 128, N / 128);
  k_zz_mfma<<<zgrid, 256, 0, stream>>>((const short*)zb, out, N);
}

// Round 4
// 408.807 us; speedup vs baseline: 3.8336x; 1.0517x over previous
//
#include <hip/hip_runtime.h>
#include <hip/hip_bf16.h>

// ---------------------------------------------------------------------------
// VGAE forward: GraphConv(256->128)+ReLU, GraphConv(128->64) x2 (fused via
// linearity), reparameterize, then sigmoid(z @ z.T) via bf16 MFMA.
// N=16384 nodes, E=262144 edges, out = [pre (N*N), z (N*64)] fp32.
// R4: dense encoder GEMMs -> MFMA with split-bf16 (hi/lo) for fp32 accuracy.
// ---------------------------------------------------------------------------

typedef short short8 __attribute__((ext_vector_type(8)));
typedef float f32x4 __attribute__((ext_vector_type(4)));

__global__ void k_deg(const int* __restrict__ src, const int* __restrict__ dst,
                      float* __restrict__ cs, float* __restrict__ cd, int E) {
  int i = blockIdx.x * blockDim.x + threadIdx.x;
  if (i < E) {
    atomicAdd(&cs[src[i]], 1.0f);
    atomicAdd(&cd[dst[i]], 1.0f);
  }
}

// Exclusive prefix sum of in-degree counts -> off[0..n]. Single block.
__global__ void __launch_bounds__(256) k_scan(const float* __restrict__ cnt,
                                              int* __restrict__ off, int n) {
  __shared__ int sums[256];
  const int t = threadIdx.x;
  const int per = n / 256;
  const int base = t * per;
  int s = 0;
  for (int i = 0; i < per; ++i) s += (int)cnt[base + i];
  sums[t] = s;
  __syncthreads();
  for (int d = 1; d < 256; d <<= 1) {
    int v = (t >= d) ? sums[t - d] : 0;
    __syncthreads();
    sums[t] += v;
    __syncthreads();
  }
  int run = t ? sums[t - 1] : 0;
  for (int i = 0; i < per; ++i) { off[base + i] = run; run += (int)cnt[base + i]; }
  if (t == 255) off[n] = run;
}

__global__ void k_cnorm(float* __restrict__ cs, float* __restrict__ cd, int n) {
  int i = blockIdx.x * blockDim.x + threadIdx.x;
  if (i < n) {
    float a = cs[i]; cs[i] = (a > 0.f) ? rsqrtf(a) : 0.f;
    float b = cd[i]; cd[i] = (b > 0.f) ? rsqrtf(b) : 0.f;
  }
}

// elist[off[d] + pos] = src, grouped by dst.
__global__ void k_fill(const int* __restrict__ src, const int* __restrict__ dst,
                       const int* __restrict__ off, int* __restrict__ cursor,
                       int* __restrict__ elist, int E) {
  int e = blockIdx.x * blockDim.x + threadIdx.x;
  if (e < E) {
    int d = dst[e];
    int pos = atomicAdd(&cursor[d], 1);
    elist[off[d] + pos] = src[e];
  }
}

// W1 [256k x 128c] -> transposed split-bf16 Wt[c][k] (hi, lo).
__global__ void k_wprep1(const float* __restrict__ W, short* __restrict__ hi,
                         short* __restrict__ lo) {
  int idx = blockIdx.x * 256 + threadIdx.x;  // 32768
  int c = idx >> 8, k = idx & 255;
  float v = W[k * 128 + c];
  __hip_bfloat16 hb = __float2bfloat16(v);
  float hf = __bfloat162float(hb);
  __hip_bfloat16 lb = __float2bfloat16(v - hf);
  hi[c * 256 + k] = *reinterpret_cast<short*>(&hb);
  lo[c * 256 + k] = *reinterpret_cast<short*>(&lb);
}

// [Wm | Ws] (each 128k x 64c) -> transposed split-bf16 W2t[c][k], c in [0,128).
__global__ void k_wprep2(const float* __restrict__ Wm, const float* __restrict__ Ws,
                         short* __restrict__ hi, short* __restrict__ lo) {
  int idx = blockIdx.x * 256 + threadIdx.x;  // 16384
  int c = idx >> 7, k = idx & 127;
  float v = (c < 64) ? Wm[k * 64 + c] : Ws[k * 64 + (c - 64)];
  __hip_bfloat16 hb = __float2bfloat16(v);
  float hf = __bfloat162float(hb);
  __hip_bfloat16 lb = __float2bfloat16(v - hf);
  hi[c * 128 + k] = *reinterpret_cast<short*>(&hb);
  lo[c * 128 + k] = *reinterpret_cast<short*>(&lb);
}

// bufA = (x * cs) @ W1 via split-bf16 MFMA. Block: 64 rows x 128 cols,
// 4 waves (32 cols each = 2 col-tiles), K=256 in 8 steps of 32.
__global__ void __launch_bounds__(256) k_enc1(const float* __restrict__ x,
                                              const short* __restrict__ wt_hi,
                                              const short* __restrict__ wt_lo,
                                              const float* __restrict__ cs,
                                              float* __restrict__ out) {
  const int wave = threadIdx.x >> 6, lane = threadIdx.x & 63;
  const int lrow = lane & 15, kq = lane >> 4;
  const int brow = blockIdx.x * 64;
  const int bcol = wave * 32;

  f32x4 acc[4][2];
#pragma unroll
  for (int i = 0; i < 4; ++i)
#pragma unroll
    for (int j = 0; j < 2; ++j) acc[i][j] = (f32x4){0.f, 0.f, 0.f, 0.f};

  float crow[4];
#pragma unroll
  for (int i = 0; i < 4; ++i) crow[i] = cs[brow + i * 16 + lrow];

  for (int ks = 0; ks < 8; ++ks) {
    short8 ahi[4], alo[4];
#pragma unroll
    for (int i = 0; i < 4; ++i) {
      const float* ap = x + (size_t)(brow + i * 16 + lrow) * 256 + ks * 32 + kq * 8;
      f32x4 a0 = *reinterpret_cast<const f32x4*>(ap);
      f32x4 a1 = *reinterpret_cast<const f32x4*>(ap + 4);
      const float c = crow[i];
      float vals[8] = {a0.x, a0.y, a0.z, a0.w, a1.x, a1.y, a1.z, a1.w};
      short8 h, l;
#pragma unroll
      for (int j = 0; j < 8; ++j) {
        float v = vals[j] * c;
        __hip_bfloat16 hb = __float2bfloat16(v);
        float hf = __bfloat162float(hb);
        __hip_bfloat16 lb = __float2bfloat16(v - hf);
        h[j] = *reinterpret_cast<short*>(&hb);
        l[j] = *reinterpret_cast<short*>(&lb);
      }
      ahi[i] = h; alo[i] = l;
    }
    short8 bhi[2], blo[2];
#pragma unroll
    for (int j = 0; j < 2; ++j) {
      size_t boff = (size_t)(bcol + j * 16 + lrow) * 256 + ks * 32 + kq * 8;
      bhi[j] = *reinterpret_cast<const short8*>(wt_hi + boff);
      blo[j] = *reinterpret_cast<const short8*>(wt_lo + boff);
    }
#pragma unroll
    for (int i = 0; i < 4; ++i)
#pragma unroll
      for (int j = 0; j < 2; ++j) {
        acc[i][j] = __builtin_amdgcn_mfma_f32_16x16x32_bf16(ahi[i], bhi[j], acc[i][j], 0, 0, 0);
        acc[i][j] = __builtin_amdgcn_mfma_f32_16x16x32_bf16(ahi[i], blo[j], acc[i][j], 0, 0, 0);
        acc[i][j] = __builtin_amdgcn_mfma_f32_16x16x32_bf16(alo[i], bhi[j], acc[i][j], 0, 0, 0);
      }
  }
#pragma unroll
  for (int i = 0; i < 4; ++i)
#pragma unroll
    for (int r = 0; r < 4; ++r) {
      int row = brow + i * 16 + kq * 4 + r;
#pragma unroll
      for (int j = 0; j < 2; ++j)
        out[(size_t)row * 128 + bcol + j * 16 + lrow] = acc[i][j][r];
    }
}

// Layer-1 CSR gather + epilogue. hs = relu(agg*cd + b1) * cs.
__global__ void __launch_bounds__(256) k_gather1(const float* __restrict__ tmp,
                                                 const int* __restrict__ off,
                                                 const int* __restrict__ elist,
                                                 const float* __restrict__ cd,
                                                 const float* __restrict__ cs,
                                                 const float* __restrict__ b,
                                                 float* __restrict__ hs) {
  const int node = blockIdx.x * 4 + (threadIdx.x >> 6);
  const int lane = threadIdx.x & 63;
  const int half = lane >> 5;
  const int c4 = (lane & 31) << 2;
  const int e0 = off[node], e1 = off[node + 1];
  f32x4 a = {0.f, 0.f, 0.f, 0.f};
  for (int e = e0 + half; e < e1; e += 2)
    a += *reinterpret_cast<const f32x4*>(tmp + (size_t)elist[e] * 128 + c4);
  a.x += __shfl_xor(a.x, 32);
  a.y += __shfl_xor(a.y, 32);
  a.z += __shfl_xor(a.z, 32);
  a.w += __shfl_xor(a.w, 32);
  if (half == 0) {
    const float c = cd[node], s = cs[node];
    f32x4 bb = *reinterpret_cast<const f32x4*>(b + c4);
    f32x4 r;
    r.x = fmaxf(a.x * c + bb.x, 0.f) * s;
    r.y = fmaxf(a.y * c + bb.y, 0.f) * s;
    r.z = fmaxf(a.z * c + bb.z, 0.f) * s;
    r.w = fmaxf(a.w * c + bb.w, 0.f) * s;
    *reinterpret_cast<f32x4*>(hs + (size_t)node * 128 + c4) = r;
  }
}

// Layer-2/3 shared aggregation: s2c[node] = cd[node] * sum_{src} hs[src]
__global__ void __launch_bounds__(256) k_gather2(const float* __restrict__ hs,
                                                 const int* __restrict__ off,
                                                 const int* __restrict__ elist,
                                                 const float* __restrict__ cd,
                                                 float* __restrict__ s2c) {
  const int node = blockIdx.x * 4 + (threadIdx.x >> 6);
  const int lane = threadIdx.x & 63;
  const int half = lane >> 5;
  const int c4 = (lane & 31) << 2;
  const int e0 = off[node], e1 = off[node + 1];
  f32x4 a = {0.f, 0.f, 0.f, 0.f};
  for (int e = e0 + half; e < e1; e += 2)
    a += *reinterpret_cast<const f32x4*>(hs + (size_t)elist[e] * 128 + c4);
  a.x += __shfl_xor(a.x, 32);
  a.y += __shfl_xor(a.y, 32);
  a.z += __shfl_xor(a.z, 32);
  a.w += __shfl_xor(a.w, 32);
  if (half == 0) {
    const float c = cd[node];
    *reinterpret_cast<f32x4*>(s2c + (size_t)node * 128 + c4) = a * c;
  }
}

// z-finish via split-bf16 MFMA: ys = s2c @ [Wm|Ws] + [bm|bs], then
// z = ys[:, :64] + noise * exp(ys[:, 64:]); also bf16 copy of z.
// Block: 64 rows x 128 cols, 4 waves, K=128 in 4 steps.
__global__ void __launch_bounds__(256) k_zfin2(const float* __restrict__ s2c,
                                               const short* __restrict__ wt_hi,
                                               const short* __restrict__ wt_lo,
                                               const float* __restrict__ bm,
                                               const float* __restrict__ bs,
                                               const float* __restrict__ noise,
                                               float* __restrict__ z,
                                               __hip_bfloat16* __restrict__ zb) {
  __shared__ float ys[64][128];
  const int wave = threadIdx.x >> 6, lane = threadIdx.x & 63;
  const int lrow = lane & 15, kq = lane >> 4;
  const int brow = blockIdx.x * 64;
  const int bcol = wave * 32;

  f32x4 acc[4][2];
#pragma unroll
  for (int i = 0; i < 4; ++i)
#pragma unroll
    for (int j = 0; j < 2; ++j) acc[i][j] = (f32x4){0.f, 0.f, 0.f, 0.f};

  for (int ks = 0; ks < 4; ++ks) {
    short8 ahi[4], alo[4];
#pragma unroll
    for (int i = 0; i < 4; ++i) {
      const float* ap = s2c + (size_t)(brow + i * 16 + lrow) * 128 + ks * 32 + kq * 8;
      f32x4 a0 = *reinterpret_cast<const f32x4*>(ap);
      f32x4 a1 = *reinterpret_cast<const f32x4*>(ap + 4);
      float vals[8] = {a0.x, a0.y, a0.z, a0.w, a1.x, a1.y, a1.z, a1.w};
      short8 h, l;
#pragma unroll
      for (int j = 0; j < 8; ++j) {
        float v = vals[j];
        __hip_bfloat16 hb = __float2bfloat16(v);
        float hf = __bfloat162float(hb);
        __hip_bfloat16 lb = __float2bfloat16(v - hf);
        h[j] = *reinterpret_cast<short*>(&hb);
        l[j] = *reinterpret_cast<short*>(&lb);
      }
      ahi[i] = h; alo[i] = l;
    }
    short8 bhi[2], blo[2];
#pragma unroll
    for (int j = 0; j < 2; ++j) {
      size_t boff = (size_t)(bcol + j * 16 + lrow) * 128 + ks * 32 + kq * 8;
      bhi[j] = *reinterpret_cast<const short8*>(wt_hi + boff);
      blo[j] = *reinterpret_cast<const short8*>(wt_lo + boff);
    }
#pragma unroll
    for (int i = 0; i < 4; ++i)
#pragma unroll
      for (int j = 0; j < 2; ++j) {
        acc[i][j] = __builtin_amdgcn_mfma_f32_16x16x32_bf16(ahi[i], bhi[j], acc[i][j], 0, 0, 0);
        acc[i][j] = __builtin_amdgcn_mfma_f32_16x16x32_bf16(ahi[i], blo[j], acc[i][j], 0, 0, 0);
        acc[i][j] = __builtin_amdgcn_mfma_f32_16x16x32_bf16(alo[i], bhi[j], acc[i][j], 0, 0, 0);
      }
  }
  // bias + stage to LDS
#pragma unroll
  for (int j = 0; j < 2; ++j) {
    const int col = bcol + j * 16 + lrow;
    const float bias = (col < 64) ? bm[col] : bs[col - 64];
#pragma unroll
    for (int i = 0; i < 4; ++i)
#pragma unroll
      for (int r = 0; r < 4; ++r)
        ys[i * 16 + kq * 4 + r][col] = acc[i][j][r] + bias;
  }
  __syncthreads();
  const int t = threadIdx.x;
#pragma unroll
  for (int q = 0; q < 16; ++q) {
    int idx = t + 256 * q;  // 0..4095
    int row = idx >> 6, c = idx & 63;
    float m = ys[row][c], ls = ys[row][c + 64];
    float zv = m + noise[(size_t)(brow + row) * 64 + c] * __expf(ls);
    z[(size_t)(brow + row) * 64 + c]  = zv;
    zb[(size_t)(brow + row) * 64 + c] = __float2bfloat16(zv);
  }
}

// pre[i,j] = sigmoid(dot(z[i,:], z[j,:])) via mfma_f32_16x16x32_bf16.
__global__ void __launch_bounds__(256) k_zz_mfma(const short* __restrict__ zb,
                                                 float* __restrict__ pre, int n) {
  const int wave = threadIdx.x >> 6, lane = threadIdx.x & 63;
  const int wr = wave >> 1, wc = wave & 1;
  const int brow = blockIdx.y * 128 + wr * 64;
  const int bcol = blockIdx.x * 128 + wc * 64;
  const int lrow = lane & 15;
  const int kq = lane >> 4;

  short8 afrag[2][4], bfrag[2][4];
#pragma unroll
  for (int tt = 0; tt < 4; ++tt) {
#pragma unroll
    for (int ks = 0; ks < 2; ++ks) {
      afrag[ks][tt] = *reinterpret_cast<const short8*>(
          zb + (size_t)(brow + tt * 16 + lrow) * 64 + ks * 32 + kq * 8);
      bfrag[ks][tt] = *reinterpret_cast<const short8*>(
          zb + (size_t)(bcol + tt * 16 + lrow) * 64 + ks * 32 + kq * 8);
    }
  }

  f32x4 acc[4][4];
#pragma unroll
  for (int i = 0; i < 4; ++i)
#pragma unroll
    for (int j = 0; j < 4; ++j) acc[i][j] = (f32x4){0.f, 0.f, 0.f, 0.f};

#pragma unroll
  for (int i = 0; i < 4; ++i)
#pragma unroll
    for (int j = 0; j < 4; ++j) {
      acc[i][j] = __builtin_amdgcn_mfma_f32_16x16x32_bf16(afrag[0][i], bfrag[0][j], acc[i][j], 0, 0, 0);
      acc[i][j] = __builtin_amdgcn_mfma_f32_16x16x32_bf16(afrag[1][i], bfrag[1][j], acc[i][j], 0, 0, 0);
    }

  const int crow0 = kq * 4;
#pragma unroll
  for (int i = 0; i < 4; ++i) {
#pragma unroll
    for (int r = 0; r < 4; ++r) {
      size_t rowoff = (size_t)(brow + i * 16 + crow0 + r) * (size_t)n;
#pragma unroll
      for (int j = 0; j < 4; ++j) {
        float v = acc[i][j][r];
        pre[rowoff + bcol + j * 16 + lrow] = 1.f / (1.f + __expf(-v));
      }
    }
  }
}

extern "C" void kernel_launch(void* const* d_in, const int* in_sizes, int n_in,
                              void* d_out, int out_size, void* d_ws, size_t ws_size,
                              hipStream_t stream) {
  const float* feat  = (const float*)d_in[0];
  const float* W1    = (const float*)d_in[1];
  const float* b1    = (const float*)d_in[2];
  const float* Wm    = (const float*)d_in[3];
  const float* bm    = (const float*)d_in[4];
  const float* Ws    = (const float*)d_in[5];
  const float* bs    = (const float*)d_in[6];
  const float* noise = (const float*)d_in[7];
  const int* esrc    = (const int*)d_in[8];
  const int* edst    = (const int*)d_in[9];

  const int N = in_sizes[0] / 256;   // 16384
  const int E = in_sizes[8];         // 262144

  float* out = (float*)d_out;
  float* z   = out + (size_t)N * N;  // z lives in d_out after pre

  char* ws = (char*)d_ws;
  float* c_src  = (float*)(ws + 0);                 // [N]
  float* c_dst  = (float*)(ws + 65536);             // [N]
  int*   cursor = (int*)  (ws + 131072);            // [N]
  int*   off    = (int*)  (ws + 196608);            // [N+1]
  int*   elist  = (int*)  (ws + 327680);            // [E] -> ends 1376256
  short* w1t_hi = (short*)(ws + 1376256);           // [128][256]
  short* w1t_lo = (short*)(ws + 1441792);
  short* w2t_hi = (short*)(ws + 1507328);           // [128][128]
  short* w2t_lo = (short*)(ws + 1540096);           // ends 1572864
  float* bufA   = (float*)(ws + 2097152);           // [N,128] xw1 out, then s2c
  float* hs     = (float*)(ws + 10485760);          // [N,128] relu(h)*cs
  __hip_bfloat16* zb = (__hip_bfloat16*)(ws + 18874368);  // [N,64] bf16 z

  // weight prep (independent)
  k_wprep1<<<128, 256, 0, stream>>>(W1, w1t_hi, w1t_lo);
  k_wprep2<<<64, 256, 0, stream>>>(Wm, Ws, w2t_hi, w2t_lo);

  // degree counts + CSR offsets + norms + edge lists
  hipMemsetAsync(ws, 0, 196608, stream);  // c_src, c_dst, cursor
  k_deg<<<(E + 255) / 256, 256, 0, stream>>>(esrc, edst, c_src, c_dst, E);
  k_scan<<<1, 256, 0, stream>>>(c_dst, off, N);
  k_cnorm<<<(N + 255) / 256, 256, 0, stream>>>(c_src, c_dst, N);
  k_fill<<<(E + 255) / 256, 256, 0, stream>>>(esrc, edst, off, cursor, elist, E);

  // layer 1: bufA = (x*cs)@W1 ; gather -> hs = relu(agg*cd+b1)*cs
  k_enc1<<<N / 64, 256, 0, stream>>>(feat, w1t_hi, w1t_lo, c_src, bufA);
  k_gather1<<<N / 4, 256, 0, stream>>>(bufA, off, elist, c_dst, c_src, b1, hs);

  // layers 2+3: s2c = cd * agg(hs) ; z = GEMM + reparam
  k_gather2<<<N / 4, 256, 0, stream>>>(hs, off, elist, c_dst, bufA);
  k_zfin2<<<N / 64, 256, 0, stream>>>(bufA, w2t_hi, w2t_lo, bm, bs, noise, z, zb);

  // decoder: pre = sigmoid(z @ z.T), bf16 MFMA
  dim3 zgrid(N / 128, N / 128);
  k_zz_mfma<<<zgrid, 256, 0, stream>>>((const short*)zb, out, N);
}

// Round 5
// 371.673 us; speedup vs baseline: 4.2167x; 1.0999x over previous
//
#include <hip/hip_runtime.h>
#include <hip/hip_bf16.h>

// ---------------------------------------------------------------------------
// VGAE forward: GraphConv(256->128)+ReLU, GraphConv(128->64) x2 (fused via
// linearity), reparameterize, then sigmoid(z @ z.T) via bf16 MFMA.
// N=16384 nodes, E=262144 edges, out = [pre (N*N), z (N*64)] fp32.
// R5: bf16 gather tables (halve L2/LLC traffic); rcp-based sigmoid epilogue.
// ---------------------------------------------------------------------------

typedef short short8 __attribute__((ext_vector_type(8)));
typedef short short4v __attribute__((ext_vector_type(4)));
typedef float f32x4 __attribute__((ext_vector_type(4)));

__device__ __forceinline__ float bf2f(short s) {
  unsigned int u = ((unsigned int)(unsigned short)s) << 16;
  return __uint_as_float(u);
}

__global__ void k_deg(const int* __restrict__ src, const int* __restrict__ dst,
                      float* __restrict__ cs, float* __restrict__ cd, int E) {
  int i = blockIdx.x * blockDim.x + threadIdx.x;
  if (i < E) {
    atomicAdd(&cs[src[i]], 1.0f);
    atomicAdd(&cd[dst[i]], 1.0f);
  }
}

// Exclusive prefix sum of in-degree counts -> off[0..n]. Single block.
__global__ void __launch_bounds__(256) k_scan(const float* __restrict__ cnt,
                                              int* __restrict__ off, int n) {
  __shared__ int sums[256];
  const int t = threadIdx.x;
  const int per = n / 256;
  const int base = t * per;
  int s = 0;
  for (int i = 0; i < per; ++i) s += (int)cnt[base + i];
  sums[t] = s;
  __syncthreads();
  for (int d = 1; d < 256; d <<= 1) {
    int v = (t >= d) ? sums[t - d] : 0;
    __syncthreads();
    sums[t] += v;
    __syncthreads();
  }
  int run = t ? sums[t - 1] : 0;
  for (int i = 0; i < per; ++i) { off[base + i] = run; run += (int)cnt[base + i]; }
  if (t == 255) off[n] = run;
}

__global__ void k_cnorm(float* __restrict__ cs, float* __restrict__ cd, int n) {
  int i = blockIdx.x * blockDim.x + threadIdx.x;
  if (i < n) {
    float a = cs[i]; cs[i] = (a > 0.f) ? rsqrtf(a) : 0.f;
    float b = cd[i]; cd[i] = (b > 0.f) ? rsqrtf(b) : 0.f;
  }
}

// elist[off[d] + pos] = src, grouped by dst.
__global__ void k_fill(const int* __restrict__ src, const int* __restrict__ dst,
                       const int* __restrict__ off, int* __restrict__ cursor,
                       int* __restrict__ elist, int E) {
  int e = blockIdx.x * blockDim.x + threadIdx.x;
  if (e < E) {
    int d = dst[e];
    int pos = atomicAdd(&cursor[d], 1);
    elist[off[d] + pos] = src[e];
  }
}

// W1 [256k x 128c] -> transposed split-bf16 Wt[c][k] (hi, lo).
__global__ void k_wprep1(const float* __restrict__ W, short* __restrict__ hi,
                         short* __restrict__ lo) {
  int idx = blockIdx.x * 256 + threadIdx.x;  // 32768
  int c = idx >> 8, k = idx & 255;
  float v = W[k * 128 + c];
  __hip_bfloat16 hb = __float2bfloat16(v);
  float hf = __bfloat162float(hb);
  __hip_bfloat16 lb = __float2bfloat16(v - hf);
  hi[c * 256 + k] = *reinterpret_cast<short*>(&hb);
  lo[c * 256 + k] = *reinterpret_cast<short*>(&lb);
}

// [Wm | Ws] (each 128k x 64c) -> transposed split-bf16 W2t[c][k], c in [0,128).
__global__ void k_wprep2(const float* __restrict__ Wm, const float* __restrict__ Ws,
                         short* __restrict__ hi, short* __restrict__ lo) {
  int idx = blockIdx.x * 256 + threadIdx.x;  // 16384
  int c = idx >> 7, k = idx & 127;
  float v = (c < 64) ? Wm[k * 64 + c] : Ws[k * 64 + (c - 64)];
  __hip_bfloat16 hb = __float2bfloat16(v);
  float hf = __bfloat162float(hb);
  __hip_bfloat16 lb = __float2bfloat16(v - hf);
  hi[c * 128 + k] = *reinterpret_cast<short*>(&hb);
  lo[c * 128 + k] = *reinterpret_cast<short*>(&lb);
}

// bufA = (x * cs) @ W1 via split-bf16 MFMA, output bf16. Block: 64 rows x
// 128 cols, 4 waves (32 cols each), K=256 in 8 steps of 32.
__global__ void __launch_bounds__(256) k_enc1(const float* __restrict__ x,
                                              const short* __restrict__ wt_hi,
                                              const short* __restrict__ wt_lo,
                                              const float* __restrict__ cs,
                                              __hip_bfloat16* __restrict__ out) {
  const int wave = threadIdx.x >> 6, lane = threadIdx.x & 63;
  const int lrow = lane & 15, kq = lane >> 4;
  const int brow = blockIdx.x * 64;
  const int bcol = wave * 32;

  f32x4 acc[4][2];
#pragma unroll
  for (int i = 0; i < 4; ++i)
#pragma unroll
    for (int j = 0; j < 2; ++j) acc[i][j] = (f32x4){0.f, 0.f, 0.f, 0.f};

  float crow[4];
#pragma unroll
  for (int i = 0; i < 4; ++i) crow[i] = cs[brow + i * 16 + lrow];

  for (int ks = 0; ks < 8; ++ks) {
    short8 ahi[4], alo[4];
#pragma unroll
    for (int i = 0; i < 4; ++i) {
      const float* ap = x + (size_t)(brow + i * 16 + lrow) * 256 + ks * 32 + kq * 8;
      f32x4 a0 = *reinterpret_cast<const f32x4*>(ap);
      f32x4 a1 = *reinterpret_cast<const f32x4*>(ap + 4);
      const float c = crow[i];
      float vals[8] = {a0.x, a0.y, a0.z, a0.w, a1.x, a1.y, a1.z, a1.w};
      short8 h, l;
#pragma unroll
      for (int j = 0; j < 8; ++j) {
        float v = vals[j] * c;
        __hip_bfloat16 hb = __float2bfloat16(v);
        float hf = __bfloat162float(hb);
        __hip_bfloat16 lb = __float2bfloat16(v - hf);
        h[j] = *reinterpret_cast<short*>(&hb);
        l[j] = *reinterpret_cast<short*>(&lb);
      }
      ahi[i] = h; alo[i] = l;
    }
    short8 bhi[2], blo[2];
#pragma unroll
    for (int j = 0; j < 2; ++j) {
      size_t boff = (size_t)(bcol + j * 16 + lrow) * 256 + ks * 32 + kq * 8;
      bhi[j] = *reinterpret_cast<const short8*>(wt_hi + boff);
      blo[j] = *reinterpret_cast<const short8*>(wt_lo + boff);
    }
#pragma unroll
    for (int i = 0; i < 4; ++i)
#pragma unroll
      for (int j = 0; j < 2; ++j) {
        acc[i][j] = __builtin_amdgcn_mfma_f32_16x16x32_bf16(ahi[i], bhi[j], acc[i][j], 0, 0, 0);
        acc[i][j] = __builtin_amdgcn_mfma_f32_16x16x32_bf16(ahi[i], blo[j], acc[i][j], 0, 0, 0);
        acc[i][j] = __builtin_amdgcn_mfma_f32_16x16x32_bf16(alo[i], bhi[j], acc[i][j], 0, 0, 0);
      }
  }
#pragma unroll
  for (int i = 0; i < 4; ++i)
#pragma unroll
    for (int r = 0; r < 4; ++r) {
      int row = brow + i * 16 + kq * 4 + r;
#pragma unroll
      for (int j = 0; j < 2; ++j)
        out[(size_t)row * 128 + bcol + j * 16 + lrow] = __float2bfloat16(acc[i][j][r]);
    }
}

// Layer-1 CSR gather (bf16 table) + epilogue. hs = bf16(relu(agg*cd+b1)*cs).
__global__ void __launch_bounds__(256) k_gather1(const short* __restrict__ tmp,
                                                 const int* __restrict__ off,
                                                 const int* __restrict__ elist,
                                                 const float* __restrict__ cd,
                                                 const float* __restrict__ cs,
                                                 const float* __restrict__ b,
                                                 short* __restrict__ hs) {
  const int node = blockIdx.x * 4 + (threadIdx.x >> 6);
  const int lane = threadIdx.x & 63;
  const int half = lane >> 5;
  const int c4 = (lane & 31) << 2;
  const int e0 = off[node], e1 = off[node + 1];
  f32x4 a = {0.f, 0.f, 0.f, 0.f};
  for (int e = e0 + half; e < e1; e += 2) {
    short4v v = *reinterpret_cast<const short4v*>(tmp + (size_t)elist[e] * 128 + c4);
    a.x += bf2f(v[0]); a.y += bf2f(v[1]); a.z += bf2f(v[2]); a.w += bf2f(v[3]);
  }
  a.x += __shfl_xor(a.x, 32);
  a.y += __shfl_xor(a.y, 32);
  a.z += __shfl_xor(a.z, 32);
  a.w += __shfl_xor(a.w, 32);
  if (half == 0) {
    const float c = cd[node], s = cs[node];
    f32x4 bb = *reinterpret_cast<const f32x4*>(b + c4);
    short4v r;
    {
      __hip_bfloat16 t0 = __float2bfloat16(fmaxf(a.x * c + bb.x, 0.f) * s);
      __hip_bfloat16 t1 = __float2bfloat16(fmaxf(a.y * c + bb.y, 0.f) * s);
      __hip_bfloat16 t2 = __float2bfloat16(fmaxf(a.z * c + bb.z, 0.f) * s);
      __hip_bfloat16 t3 = __float2bfloat16(fmaxf(a.w * c + bb.w, 0.f) * s);
      r[0] = *reinterpret_cast<short*>(&t0);
      r[1] = *reinterpret_cast<short*>(&t1);
      r[2] = *reinterpret_cast<short*>(&t2);
      r[3] = *reinterpret_cast<short*>(&t3);
    }
    *reinterpret_cast<short4v*>(hs + (size_t)node * 128 + c4) = r;
  }
}

// Layer-2/3 shared aggregation: s2c[node] = cd[node] * sum_{src} hs[src] (fp32 out)
__global__ void __launch_bounds__(256) k_gather2(const short* __restrict__ hs,
                                                 const int* __restrict__ off,
                                                 const int* __restrict__ elist,
                                                 const float* __restrict__ cd,
                                                 float* __restrict__ s2c) {
  const int node = blockIdx.x * 4 + (threadIdx.x >> 6);
  const int lane = threadIdx.x & 63;
  const int half = lane >> 5;
  const int c4 = (lane & 31) << 2;
  const int e0 = off[node], e1 = off[node + 1];
  f32x4 a = {0.f, 0.f, 0.f, 0.f};
  for (int e = e0 + half; e < e1; e += 2) {
    short4v v = *reinterpret_cast<const short4v*>(hs + (size_t)elist[e] * 128 + c4);
    a.x += bf2f(v[0]); a.y += bf2f(v[1]); a.z += bf2f(v[2]); a.w += bf2f(v[3]);
  }
  a.x += __shfl_xor(a.x, 32);
  a.y += __shfl_xor(a.y, 32);
  a.z += __shfl_xor(a.z, 32);
  a.w += __shfl_xor(a.w, 32);
  if (half == 0) {
    const float c = cd[node];
    *reinterpret_cast<f32x4*>(s2c + (size_t)node * 128 + c4) = a * c;
  }
}

// z-finish via split-bf16 MFMA: ys = s2c @ [Wm|Ws] + [bm|bs], then
// z = ys[:, :64] + noise * exp(ys[:, 64:]); also bf16 copy of z.
__global__ void __launch_bounds__(256) k_zfin2(const float* __restrict__ s2c,
                                               const short* __restrict__ wt_hi,
                                               const short* __restrict__ wt_lo,
                                               const float* __restrict__ bm,
                                               const float* __restrict__ bs,
                                               const float* __restrict__ noise,
                                               float* __restrict__ z,
                                               __hip_bfloat16* __restrict__ zb) {
  __shared__ float ys[64][128];
  const int wave = threadIdx.x >> 6, lane = threadIdx.x & 63;
  const int lrow = lane & 15, kq = lane >> 4;
  const int brow = blockIdx.x * 64;
  const int bcol = wave * 32;

  f32x4 acc[4][2];
#pragma unroll
  for (int i = 0; i < 4; ++i)
#pragma unroll
    for (int j = 0; j < 2; ++j) acc[i][j] = (f32x4){0.f, 0.f, 0.f, 0.f};

  for (int ks = 0; ks < 4; ++ks) {
    short8 ahi[4], alo[4];
#pragma unroll
    for (int i = 0; i < 4; ++i) {
      const float* ap = s2c + (size_t)(brow + i * 16 + lrow) * 128 + ks * 32 + kq * 8;
      f32x4 a0 = *reinterpret_cast<const f32x4*>(ap);
      f32x4 a1 = *reinterpret_cast<const f32x4*>(ap + 4);
      float vals[8] = {a0.x, a0.y, a0.z, a0.w, a1.x, a1.y, a1.z, a1.w};
      short8 h, l;
#pragma unroll
      for (int j = 0; j < 8; ++j) {
        float v = vals[j];
        __hip_bfloat16 hb = __float2bfloat16(v);
        float hf = __bfloat162float(hb);
        __hip_bfloat16 lb = __float2bfloat16(v - hf);
        h[j] = *reinterpret_cast<short*>(&hb);
        l[j] = *reinterpret_cast<short*>(&lb);
      }
      ahi[i] = h; alo[i] = l;
    }
    short8 bhi[2], blo[2];
#pragma unroll
    for (int j = 0; j < 2; ++j) {
      size_t boff = (size_t)(bcol + j * 16 + lrow) * 128 + ks * 32 + kq * 8;
      bhi[j] = *reinterpret_cast<const short8*>(wt_hi + boff);
      blo[j] = *reinterpret_cast<const short8*>(wt_lo + boff);
    }
#pragma unroll
    for (int i = 0; i < 4; ++i)
#pragma unroll
      for (int j = 0; j < 2; ++j) {
        acc[i][j] = __builtin_amdgcn_mfma_f32_16x16x32_bf16(ahi[i], bhi[j], acc[i][j], 0, 0, 0);
        acc[i][j] = __builtin_amdgcn_mfma_f32_16x16x32_bf16(ahi[i], blo[j], acc[i][j], 0, 0, 0);
        acc[i][j] = __builtin_amdgcn_mfma_f32_16x16x32_bf16(alo[i], bhi[j], acc[i][j], 0, 0, 0);
      }
  }
#pragma unroll
  for (int j = 0; j < 2; ++j) {
    const int col = bcol + j * 16 + lrow;
    const float bias = (col < 64) ? bm[col] : bs[col - 64];
#pragma unroll
    for (int i = 0; i < 4; ++i)
#pragma unroll
      for (int r = 0; r < 4; ++r)
        ys[i * 16 + kq * 4 + r][col] = acc[i][j][r] + bias;
  }
  __syncthreads();
  const int t = threadIdx.x;
#pragma unroll
  for (int q = 0; q < 16; ++q) {
    int idx = t + 256 * q;  // 0..4095
    int row = idx >> 6, c = idx & 63;
    float m = ys[row][c], ls = ys[row][c + 64];
    float zv = m + noise[(size_t)(brow + row) * 64 + c] * __expf(ls);
    z[(size_t)(brow + row) * 64 + c]  = zv;
    zb[(size_t)(brow + row) * 64 + c] = __float2bfloat16(zv);
  }
}

// pre[i,j] = sigmoid(dot(z[i,:], z[j,:])) via mfma_f32_16x16x32_bf16.
__global__ void __launch_bounds__(256) k_zz_mfma(const short* __restrict__ zb,
                                                 float* __restrict__ pre, int n) {
  const int wave = threadIdx.x >> 6, lane = threadIdx.x & 63;
  const int wr = wave >> 1, wc = wave & 1;
  const int brow = blockIdx.y * 128 + wr * 64;
  const int bcol = blockIdx.x * 128 + wc * 64;
  const int lrow = lane & 15;
  const int kq = lane >> 4;

  short8 afrag[2][4], bfrag[2][4];
#pragma unroll
  for (int tt = 0; tt < 4; ++tt) {
#pragma unroll
    for (int ks = 0; ks < 2; ++ks) {
      afrag[ks][tt] = *reinterpret_cast<const short8*>(
          zb + (size_t)(brow + tt * 16 + lrow) * 64 + ks * 32 + kq * 8);
      bfrag[ks][tt] = *reinterpret_cast<const short8*>(
          zb + (size_t)(bcol + tt * 16 + lrow) * 64 + ks * 32 + kq * 8);
    }
  }

  f32x4 acc[4][4];
#pragma unroll
  for (int i = 0; i < 4; ++i)
#pragma unroll
    for (int j = 0; j < 4; ++j) acc[i][j] = (f32x4){0.f, 0.f, 0.f, 0.f};

#pragma unroll
  for (int i = 0; i < 4; ++i)
#pragma unroll
    for (int j = 0; j < 4; ++j) {
      acc[i][j] = __builtin_amdgcn_mfma_f32_16x16x32_bf16(afrag[0][i], bfrag[0][j], acc[i][j], 0, 0, 0);
      acc[i][j] = __builtin_amdgcn_mfma_f32_16x16x32_bf16(afrag[1][i], bfrag[1][j], acc[i][j], 0, 0, 0);
    }

  const int crow0 = kq * 4;
#pragma unroll
  for (int i = 0; i < 4; ++i) {
#pragma unroll
    for (int r = 0; r < 4; ++r) {
      size_t rowoff = (size_t)(brow + i * 16 + crow0 + r) * (size_t)n;
#pragma unroll
      for (int j = 0; j < 4; ++j) {
        float e = __expf(-acc[i][j][r]);
        pre[rowoff + bcol + j * 16 + lrow] = __builtin_amdgcn_rcpf(1.f + e);
      }
    }
  }
}

extern "C" void kernel_launch(void* const* d_in, const int* in_sizes, int n_in,
                              void* d_out, int out_size, void* d_ws, size_t ws_size,
                              hipStream_t stream) {
  const float* feat  = (const float*)d_in[0];
  const float* W1    = (const float*)d_in[1];
  const float* b1    = (const float*)d_in[2];
  const float* Wm    = (const float*)d_in[3];
  const float* bm    = (const float*)d_in[4];
  const float* Ws    = (const float*)d_in[5];
  const float* bs    = (const float*)d_in[6];
  const float* noise = (const float*)d_in[7];
  const int* esrc    = (const int*)d_in[8];
  const int* edst    = (const int*)d_in[9];

  const int N = in_sizes[0] / 256;   // 16384
  const int E = in_sizes[8];         // 262144

  float* out = (float*)d_out;
  float* z   = out + (size_t)N * N;  // z lives in d_out after pre

  char* ws = (char*)d_ws;
  float* c_src  = (float*)(ws + 0);                 // [N]
  float* c_dst  = (float*)(ws + 65536);             // [N]
  int*   cursor = (int*)  (ws + 131072);            // [N]
  int*   off    = (int*)  (ws + 196608);            // [N+1]
  int*   elist  = (int*)  (ws + 327680);            // [E] -> ends 1376256
  short* w1t_hi = (short*)(ws + 1376256);           // [128][256]
  short* w1t_lo = (short*)(ws + 1441792);
  short* w2t_hi = (short*)(ws + 1507328);           // [128][128]
  short* w2t_lo = (short*)(ws + 1540096);           // ends 1572864
  short* bufA   = (short*)(ws + 2097152);           // [N][128] bf16 xw1 out
  short* hsb    = (short*)(ws + 6291456);           // [N][128] bf16 relu(h)*cs
  float* s2c    = (float*)(ws + 10485760);          // [N][128] fp32 -> ends 18874368
  __hip_bfloat16* zb = (__hip_bfloat16*)(ws + 18874368);  // [N,64] bf16 z

  // weight prep (independent)
  k_wprep1<<<128, 256, 0, stream>>>(W1, w1t_hi, w1t_lo);
  k_wprep2<<<64, 256, 0, stream>>>(Wm, Ws, w2t_hi, w2t_lo);

  // degree counts + CSR offsets + norms + edge lists
  hipMemsetAsync(ws, 0, 196608, stream);  // c_src, c_dst, cursor
  k_deg<<<(E + 255) / 256, 256, 0, stream>>>(esrc, edst, c_src, c_dst, E);
  k_scan<<<1, 256, 0, stream>>>(c_dst, off, N);
  k_cnorm<<<(N + 255) / 256, 256, 0, stream>>>(c_src, c_dst, N);
  k_fill<<<(E + 255) / 256, 256, 0, stream>>>(esrc, edst, off, cursor, elist, E);

  // layer 1: bufA = bf16((x*cs)@W1) ; gather -> hsb = bf16(relu(agg*cd+b1)*cs)
  k_enc1<<<N / 64, 256, 0, stream>>>(feat, w1t_hi, w1t_lo, c_src, (__hip_bfloat16*)bufA);
  k_gather1<<<N / 4, 256, 0, stream>>>(bufA, off, elist, c_dst, c_src, b1, hsb);

  // layers 2+3: s2c = cd * agg(hsb) ; z = GEMM + reparam
  k_gather2<<<N / 4, 256, 0, stream>>>(hsb, off, elist, c_dst, s2c);
  k_zfin2<<<N / 64, 256, 0, stream>>>(s2c, w2t_hi, w2t_lo, bm, bs, noise, z, zb);

  // decoder: pre = sigmoid(z @ z.T), bf16 MFMA
  dim3 zgrid(N / 128, N / 128);
  k_zz_mfma<<<zgrid, 256, 0, stream>>>((const short*)zb, out, N);
}